// Round 10
// baseline (198.989 us; speedup 1.0000x reference)
//
#include <hip/hip_runtime.h>

// ---------------------------------------------------------------------------
// Temporal MHA (MI355X/gfx950), B=256, S=176 (8t x 22j), D_in=128, H=8, Hd=32.
//  k0: x,W -> bf16 once (ws).
//  k1: block = (b,h), 512 thr = 8 waves, 4 blocks/CU (32 waves = full cap).
//      Grid swizzle: h = blockIdx>>8, b = blockIdx&255 -> all 8 heads of a
//      batch land on one XCD (same blockIdx mod 8) for L2 reuse of x.
//   p1: wave w owns m-tiles {w, w+8} (w<3 takes two). W/x fragments straight
//       from global (L2-hot; no WS staging, no barrier 0). Q^T stays in regs
//       (R7-verified k-slot bijection); K,V^T -> LDS in permuted col order
//       (bank-uniform b128 gathers, R9-verified).
//   p2: per owned row-tile: S^T = K*Q^T (11 MFMA), mask, exp2-softmax
//       (unnormalized, 1/sum in epilogue), P^T in regs, O^T = V^T*P^T
//       (12 MFMA), float4 stores.
// k-slot bijection sigma(q,j) = (j<4 ? q*4+j : 16+q*4+(j-4)); KS col
// s=(c>>2)*8+nt*4+(c&3); VT col s=(mt>>1)*32+(c>>2)*8+(mt&1)*4+(c&3).
// VT pad slots (logical t' 176..191) = phys cols 160+(m>>2)*8+4+(m&3),
// disjoint from every phase-1 write -> zeroed up front, no extra barrier.
// ---------------------------------------------------------------------------

#define SEQ    176
#define HD     32
#define DIN    128
#define DMODEL 256

typedef unsigned short ushort_t;
typedef __attribute__((ext_vector_type(8))) short short8;
typedef __attribute__((ext_vector_type(4))) short short4v;
typedef __attribute__((ext_vector_type(4))) float float4v;
typedef __attribute__((ext_vector_type(4))) unsigned short ushort4v;

// ws layout (bytes): WT bf16 [3][8][32][128] @ 0; X16 bf16 [256*176*128] @ 196608
#define WS_WT 0u
#define WS_X  196608u

// LDS (ushort units), total 13440 ush = 26880 B -> 4 blocks/CU (wave-capped)
//  KS @ 0     [176][40] = 7040   (K, permuted cols)
//  VT @ 7040  [32][200] = 6400   (V^T, permuted cols; pad slots zeroed)
#define SMEM_TOTAL 13440
#define OFF_VT 7040

__device__ __forceinline__ ushort_t f2bf_rtne(float f) {
    union { float f; unsigned int u; } cv; cv.f = f;
    unsigned int u = cv.u;
    unsigned int rb = 0x7FFFu + ((u >> 16) & 1u);
    return (ushort_t)((u + rb) >> 16);
}
__device__ __forceinline__ ushort_t f2bf(float f) {   // round-half-up, 2 VALU
    union { float f; unsigned int u; } cv; cv.f = f;
    return (ushort_t)((cv.u + 0x8000u) >> 16);
}

// ---------------- k0: one-shot bf16 conversion ----------------------------
__global__ __launch_bounds__(256)
void k0_conv(const float* __restrict__ x,
             const float* __restrict__ Wq, const float* __restrict__ Wk,
             const float* __restrict__ Wv,
             ushort_t* __restrict__ WT, ushort_t* __restrict__ X16)
{
    int bid = blockIdx.x;
    if (bid < 5632) {
        int f4 = bid * 256 + threadIdx.x;
        float4 v = reinterpret_cast<const float4*>(x)[f4];
        ushort4v o;
        o.x = f2bf_rtne(v.x); o.y = f2bf_rtne(v.y);
        o.z = f2bf_rtne(v.z); o.w = f2bf_rtne(v.w);
        reinterpret_cast<ushort4v*>(X16)[f4] = o;
    } else {
        int idx = (bid - 5632) * 256 + threadIdx.x;   // < 24576
        int e = idx * 4;
        int mat = e >> 15, h = (e >> 12) & 7, n = (e >> 7) & 31, k = e & 127;
        const float* W = (mat == 0) ? Wq : ((mat == 1) ? Wk : Wv);
        ushort4v o;
        o.x = f2bf_rtne(W[(k + 0) * DMODEL + h * HD + n]);
        o.y = f2bf_rtne(W[(k + 1) * DMODEL + h * HD + n]);
        o.z = f2bf_rtne(W[(k + 2) * DMODEL + h * HD + n]);
        o.w = f2bf_rtne(W[(k + 3) * DMODEL + h * HD + n]);
        reinterpret_cast<ushort4v*>(WT)[idx] = o;
    }
}

// ---------------- k1: fused attention -------------------------------------
__global__ __launch_bounds__(512, 8)
void k1_attn(const ushort_t* __restrict__ X16, const ushort_t* __restrict__ WT,
             const float* __restrict__ bq, const float* __restrict__ bk,
             const float* __restrict__ bv, float* __restrict__ out)
{
    __shared__ ushort_t smem[SMEM_TOTAL];
    ushort_t* KS = smem;                 // [176][40] permuted
    ushort_t* VT = smem + OFF_VT;        // [32][200] permuted

    const int tid  = threadIdx.x;
    const int lane = tid & 63;
    const int wave = tid >> 6;           // 0..7
    const int c    = lane & 15;
    const int q    = lane >> 4;
    const int b    = blockIdx.x & 255;   // XCD swizzle: same b -> same XCD
    const int h    = blockIdx.x >> 8;

    // zero exactly the 16 permuted VT pad columns (rows 0..31); these slots
    // are written by no phase-1 store, so no barrier needed before phase 1.
    {
        int row = tid >> 4, m = tid & 15;
        VT[row * 200 + 160 + (m >> 2) * 8 + 4 + (m & 3)] = 0;
    }

    const float qscale = 0.17677669529663687f * 1.4426950408889634f; // 1/sqrt(32)*log2e
    const int skv = (c >> 2) * 8 + (c & 3);          // permuted col base (K)
    short8 qf8[2];

    // ---- phase 1: QKV for owned m-tiles; W and x frags from global -------
#pragma unroll
    for (int it = 0; it < 2; ++it) {
        const int mt = wave + it * 8;
        if (mt < 11) {
            const ushort_t* xr = X16 + ((size_t)b * SEQ + mt * 16 + c) * DIN;
            short8 xf[4];
#pragma unroll
            for (int kk = 0; kk < 4; ++kk)
                xf[kk] = *reinterpret_cast<const short8*>(xr + kk * 32 + q * 8);
            const int svt = (mt >> 1) * 32 + (c >> 2) * 8 + (mt & 1) * 4 + (c & 3);

#pragma unroll
            for (int jj = 0; jj < 6; ++jj) {
                const int mat = jj >> 1, nt = jj & 1;
                const ushort_t* wrow =
                    WT + (size_t)(((mat * 8 + h) * 32 + nt * 16 + c)) * 128 + q * 8;
                float4v acc = {0.f, 0.f, 0.f, 0.f};
                if (mat == 1) {              // K normal: A=x, B=W
#pragma unroll
                    for (int kk = 0; kk < 4; ++kk) {
                        short8 wf = *reinterpret_cast<const short8*>(wrow + kk * 32);
                        acc = __builtin_amdgcn_mfma_f32_16x16x32_bf16(xf[kk], wf, acc, 0, 0, 0);
                    }
                } else {                     // Q^T / V^T: A=W, B=x
#pragma unroll
                    for (int kk = 0; kk < 4; ++kk) {
                        short8 wf = *reinterpret_cast<const short8*>(wrow + kk * 32);
                        acc = __builtin_amdgcn_mfma_f32_16x16x32_bf16(wf, xf[kk], acc, 0, 0, 0);
                    }
                }
                if (mat == 0) {
                    float4 bb4 = *reinterpret_cast<const float4*>(bq + h * HD + nt * 16 + q * 4);
                    qf8[it][nt * 4 + 0] = (short)f2bf((acc[0] + bb4.x) * qscale);
                    qf8[it][nt * 4 + 1] = (short)f2bf((acc[1] + bb4.y) * qscale);
                    qf8[it][nt * 4 + 2] = (short)f2bf((acc[2] + bb4.z) * qscale);
                    qf8[it][nt * 4 + 3] = (short)f2bf((acc[3] + bb4.w) * qscale);
                } else if (mat == 1) {
                    float bia = bk[h * HD + nt * 16 + c];
#pragma unroll
                    for (int r = 0; r < 4; ++r)
                        KS[(mt * 16 + q * 4 + r) * 40 + skv + nt * 4] = f2bf(acc[r] + bia);
                } else {
                    float4 bb4 = *reinterpret_cast<const float4*>(bv + h * HD + nt * 16 + q * 4);
#pragma unroll
                    for (int r = 0; r < 4; ++r) {
                        float bias_r = (r == 0) ? bb4.x : (r == 1) ? bb4.y
                                      : (r == 2) ? bb4.z : bb4.w;
                        float v = acc[r] + bias_r;
                        v = v > 0.f ? v : 0.f;           // ReLU on V
                        VT[(nt * 16 + q * 4 + r) * 200 + svt] = f2bf(v);
                    }
                }
            }
        }
    }
    __syncthreads();   // barrier: KS/VT (and pad zeros) visible block-wide

    // ---- phase 2: attention for owned row-tiles --------------------------
#pragma unroll
    for (int it = 0; it < 2; ++it) {
        const int rt = wave + it * 8;
        if (rt < 11) {
            const int t_row = rt * 16 + c;
            const int lo = (t_row / 22) * 22;
            float su = 0.f;
            short8 pf[6];
            pf[5] = (short8){0, 0, 0, 0, 0, 0, 0, 0};
#pragma unroll
            for (int n = 0; n < 11; ++n) {
                short8 kf = *reinterpret_cast<const short8*>(KS + (n * 16 + c) * 40 + q * 8);
                float4v s = {0.f, 0.f, 0.f, 0.f};
                s = __builtin_amdgcn_mfma_f32_16x16x32_bf16(kf, qf8[it], s, 0, 0, 0);
#pragma unroll
                for (int r = 0; r < 4; ++r) {
                    int tp = n * 16 + q * 4 + r;
                    float sv = (((unsigned)(tp - lo) < 22u) && (tp != t_row)) ? -1e30f : s[r];
                    float e = __builtin_amdgcn_exp2f(sv);
                    su += e;
                    pf[n >> 1][(n & 1) * 4 + r] = (short)f2bf(e);
                }
            }
            su += __shfl_xor(su, 16, 64);
            su += __shfl_xor(su, 32, 64);
            const float invs = 1.0f / su;

            float* ob = out + ((size_t)b * SEQ + t_row) * DMODEL + h * HD;
#pragma unroll
            for (int mt2 = 0; mt2 < 2; ++mt2) {
                const ushort_t* vrow = VT + (mt2 * 16 + c) * 200;
                float4v o = {0.f, 0.f, 0.f, 0.f};
#pragma unroll
                for (int g = 0; g < 6; ++g) {
                    short8 vf = *reinterpret_cast<const short8*>(vrow + g * 32 + q * 8);
                    o = __builtin_amdgcn_mfma_f32_16x16x32_bf16(vf, pf[g], o, 0, 0, 0);
                }
                float4 st;
                st.x = o[0] * invs; st.y = o[1] * invs;
                st.z = o[2] * invs; st.w = o[3] * invs;
                *reinterpret_cast<float4*>(ob + mt2 * 16 + q * 4) = st;
            }
        }
    }
}

extern "C" void kernel_launch(void* const* d_in, const int* in_sizes, int n_in,
                              void* d_out, int out_size, void* d_ws, size_t ws_size,
                              hipStream_t stream) {
    const float* x  = (const float*)d_in[0];
    const float* Wq = (const float*)d_in[1];
    const float* bq = (const float*)d_in[2];
    const float* Wk = (const float*)d_in[3];
    const float* bk = (const float*)d_in[4];
    const float* Wv = (const float*)d_in[5];
    const float* bv = (const float*)d_in[6];
    float* out = (float*)d_out;

    char* ws = (char*)d_ws;
    ushort_t* WT  = (ushort_t*)(ws + WS_WT);
    ushort_t* X16 = (ushort_t*)(ws + WS_X);

    k0_conv<<<dim3(5728), dim3(256), 0, stream>>>(x, Wq, Wk, Wv, WT, X16);
    k1_attn<<<dim3(2048), dim3(512), 0, stream>>>(X16, WT, bq, bk, bv, out);
}

// Round 11
// 179.273 us; speedup vs baseline: 1.1100x; 1.1100x over previous
//
#include <hip/hip_runtime.h>

// ---------------------------------------------------------------------------
// Temporal MHA (MI355X/gfx950), B=256, S=176 (8t x 22j), D_in=128, H=8, Hd=32.
//  k0: W -> bf16 once (tiny). x is read fp32 directly by k1 (no x pre-pass).
//  k1: block = (b,h), 512 thr = 8 waves, launch_bounds(512,4) -- NO spill
//      (R10's (512,8) forced a 64-VGPR cap -> scratch spill -> 2.4x slower).
//      Grid swizzle: b = blockIdx&255, h = blockIdx>>8 -> all 8 heads of a
//      batch share an XCD; x stays L2-resident (2.9 MB/XCD).
//   p1: wave w owns m-tiles {w, w+8}; x fp32 fragments converted to bf16
//       in-register; W b128 frags from global WT (L2-hot). Q^T stays in regs
//       (k-slot bijection, R7-verified); K,V^T -> LDS permuted (R9-verified
//       bank-uniform b128 gathers).
//   p2: per owned row-tile: S^T = K*Q^T (11 MFMA), mask, exp2-softmax
//       (unnormalized, 1/sum in epilogue), P^T in regs, O^T = V^T*P^T
//       (12 MFMA), float4 stores.
// k-slot bijection sigma(q,j) = (j<4 ? q*4+j : 16+q*4+(j-4)); KS col
// s=(c>>2)*8+nt*4+(c&3); VT col s=(mt>>1)*32+(c>>2)*8+(mt&1)*4+(c&3).
// VT pad slots (logical t' 176..191) = phys cols 160+(m>>2)*8+4+(m&3),
// disjoint from every phase-1 write -> zeroed up front, no extra barrier.
// ---------------------------------------------------------------------------

#define SEQ    176
#define HD     32
#define DIN    128
#define DMODEL 256

typedef unsigned short ushort_t;
typedef __attribute__((ext_vector_type(8))) short short8;
typedef __attribute__((ext_vector_type(4))) short short4v;
typedef __attribute__((ext_vector_type(4))) float float4v;
typedef __attribute__((ext_vector_type(4))) unsigned short ushort4v;

// ws layout (bytes): WT bf16 [3][8][32][128] @ 0
#define WS_WT 0u

// LDS (ushort units), total 13440 ush = 26880 B -> up to 4 blocks/CU
//  KS @ 0     [176][40] = 7040   (K, permuted cols)
//  VT @ 7040  [32][200] = 6400   (V^T, permuted cols; pad slots zeroed)
#define SMEM_TOTAL 13440
#define OFF_VT 7040

__device__ __forceinline__ ushort_t f2bf_rtne(float f) {
    union { float f; unsigned int u; } cv; cv.f = f;
    unsigned int u = cv.u;
    unsigned int rb = 0x7FFFu + ((u >> 16) & 1u);
    return (ushort_t)((u + rb) >> 16);
}
__device__ __forceinline__ ushort_t f2bf(float f) {   // round-half-up, 2 VALU
    union { float f; unsigned int u; } cv; cv.f = f;
    return (ushort_t)((cv.u + 0x8000u) >> 16);
}

// ---------------- k0: W -> WT bf16 [mat][h][n][k] (96 blocks) -------------
__global__ __launch_bounds__(256)
void k0_conv(const float* __restrict__ Wq, const float* __restrict__ Wk,
             const float* __restrict__ Wv, ushort_t* __restrict__ WT)
{
    int idx = blockIdx.x * 256 + threadIdx.x;     // < 24576
    int e = idx * 4;
    int mat = e >> 15, h = (e >> 12) & 7, n = (e >> 7) & 31, k = e & 127;
    const float* W = (mat == 0) ? Wq : ((mat == 1) ? Wk : Wv);
    ushort4v o;
    o.x = f2bf_rtne(W[(k + 0) * DMODEL + h * HD + n]);
    o.y = f2bf_rtne(W[(k + 1) * DMODEL + h * HD + n]);
    o.z = f2bf_rtne(W[(k + 2) * DMODEL + h * HD + n]);
    o.w = f2bf_rtne(W[(k + 3) * DMODEL + h * HD + n]);
    reinterpret_cast<ushort4v*>(WT)[idx] = o;
}

// ---------------- k1: fused attention -------------------------------------
__global__ __launch_bounds__(512, 4)
void k1_attn(const float* __restrict__ x, const ushort_t* __restrict__ WT,
             const float* __restrict__ bq, const float* __restrict__ bk,
             const float* __restrict__ bv, float* __restrict__ out)
{
    __shared__ ushort_t smem[SMEM_TOTAL];
    ushort_t* KS = smem;                 // [176][40] permuted
    ushort_t* VT = smem + OFF_VT;        // [32][200] permuted

    const int tid  = threadIdx.x;
    const int lane = tid & 63;
    const int wave = tid >> 6;           // 0..7
    const int c    = lane & 15;
    const int q    = lane >> 4;
    const int b    = blockIdx.x & 255;   // XCD swizzle: same b -> same XCD
    const int h    = blockIdx.x >> 8;

    // zero exactly the 16 permuted VT pad columns (rows 0..31); these slots
    // are written by no phase-1 store, so no barrier needed before phase 1.
    {
        int row = tid >> 4, m = tid & 15;
        VT[row * 200 + 160 + (m >> 2) * 8 + 4 + (m & 3)] = 0;
    }

    const float qscale = 0.17677669529663687f * 1.4426950408889634f; // 1/sqrt(32)*log2e
    const int skv = (c >> 2) * 8 + (c & 3);          // permuted col base (K)
    short8 qf8[2];

    // ---- phase 1: QKV for owned m-tiles; x fp32 + W bf16 from global -----
#pragma unroll
    for (int it = 0; it < 2; ++it) {
        const int mt = wave + it * 8;
        if (mt < 11) {
            const float* xr = x + ((size_t)b * SEQ + mt * 16 + c) * DIN;
            short8 xf[4];
#pragma unroll
            for (int kk = 0; kk < 4; ++kk) {
                float4 a0 = *reinterpret_cast<const float4*>(xr + kk * 32 + q * 8);
                float4 a1 = *reinterpret_cast<const float4*>(xr + kk * 32 + q * 8 + 4);
                short8 v;
                v[0] = (short)f2bf(a0.x); v[1] = (short)f2bf(a0.y);
                v[2] = (short)f2bf(a0.z); v[3] = (short)f2bf(a0.w);
                v[4] = (short)f2bf(a1.x); v[5] = (short)f2bf(a1.y);
                v[6] = (short)f2bf(a1.z); v[7] = (short)f2bf(a1.w);
                xf[kk] = v;
            }
            const int svt = (mt >> 1) * 32 + (c >> 2) * 8 + (mt & 1) * 4 + (c & 3);

#pragma unroll
            for (int jj = 0; jj < 6; ++jj) {
                const int mat = jj >> 1, nt = jj & 1;
                const ushort_t* wrow =
                    WT + (size_t)(((mat * 8 + h) * 32 + nt * 16 + c)) * 128 + q * 8;
                float4v acc = {0.f, 0.f, 0.f, 0.f};
                if (mat == 1) {              // K normal: A=x, B=W
#pragma unroll
                    for (int kk = 0; kk < 4; ++kk) {
                        short8 wf = *reinterpret_cast<const short8*>(wrow + kk * 32);
                        acc = __builtin_amdgcn_mfma_f32_16x16x32_bf16(xf[kk], wf, acc, 0, 0, 0);
                    }
                } else {                     // Q^T / V^T: A=W, B=x
#pragma unroll
                    for (int kk = 0; kk < 4; ++kk) {
                        short8 wf = *reinterpret_cast<const short8*>(wrow + kk * 32);
                        acc = __builtin_amdgcn_mfma_f32_16x16x32_bf16(wf, xf[kk], acc, 0, 0, 0);
                    }
                }
                if (mat == 0) {
                    float4 bb4 = *reinterpret_cast<const float4*>(bq + h * HD + nt * 16 + q * 4);
                    qf8[it][nt * 4 + 0] = (short)f2bf((acc[0] + bb4.x) * qscale);
                    qf8[it][nt * 4 + 1] = (short)f2bf((acc[1] + bb4.y) * qscale);
                    qf8[it][nt * 4 + 2] = (short)f2bf((acc[2] + bb4.z) * qscale);
                    qf8[it][nt * 4 + 3] = (short)f2bf((acc[3] + bb4.w) * qscale);
                } else if (mat == 1) {
                    float bia = bk[h * HD + nt * 16 + c];
#pragma unroll
                    for (int r = 0; r < 4; ++r)
                        KS[(mt * 16 + q * 4 + r) * 40 + skv + nt * 4] = f2bf(acc[r] + bia);
                } else {
                    float4 bb4 = *reinterpret_cast<const float4*>(bv + h * HD + nt * 16 + q * 4);
#pragma unroll
                    for (int r = 0; r < 4; ++r) {
                        float bias_r = (r == 0) ? bb4.x : (r == 1) ? bb4.y
                                      : (r == 2) ? bb4.z : bb4.w;
                        float v = acc[r] + bias_r;
                        v = v > 0.f ? v : 0.f;           // ReLU on V
                        VT[(nt * 16 + q * 4 + r) * 200 + svt] = f2bf(v);
                    }
                }
            }
        }
    }
    __syncthreads();   // barrier: KS/VT (and pad zeros) visible block-wide

    // ---- phase 2: attention for owned row-tiles --------------------------
#pragma unroll
    for (int it = 0; it < 2; ++it) {
        const int rt = wave + it * 8;
        if (rt < 11) {
            const int t_row = rt * 16 + c;
            const int lo = (t_row / 22) * 22;
            float su = 0.f;
            short8 pf[6];
            pf[5] = (short8){0, 0, 0, 0, 0, 0, 0, 0};
#pragma unroll
            for (int n = 0; n < 11; ++n) {
                short8 kf = *reinterpret_cast<const short8*>(KS + (n * 16 + c) * 40 + q * 8);
                float4v s = {0.f, 0.f, 0.f, 0.f};
                s = __builtin_amdgcn_mfma_f32_16x16x32_bf16(kf, qf8[it], s, 0, 0, 0);
#pragma unroll
                for (int r = 0; r < 4; ++r) {
                    int tp = n * 16 + q * 4 + r;
                    float sv = (((unsigned)(tp - lo) < 22u) && (tp != t_row)) ? -1e30f : s[r];
                    float e = __builtin_amdgcn_exp2f(sv);
                    su += e;
                    pf[n >> 1][(n & 1) * 4 + r] = (short)f2bf(e);
                }
            }
            su += __shfl_xor(su, 16, 64);
            su += __shfl_xor(su, 32, 64);
            const float invs = 1.0f / su;

            float* ob = out + ((size_t)b * SEQ + t_row) * DMODEL + h * HD;
#pragma unroll
            for (int mt2 = 0; mt2 < 2; ++mt2) {
                const ushort_t* vrow = VT + (mt2 * 16 + c) * 200;
                float4v o = {0.f, 0.f, 0.f, 0.f};
#pragma unroll
                for (int g = 0; g < 6; ++g) {
                    short8 vf = *reinterpret_cast<const short8*>(vrow + g * 32 + q * 8);
                    o = __builtin_amdgcn_mfma_f32_16x16x32_bf16(vf, pf[g], o, 0, 0, 0);
                }
                float4 st;
                st.x = o[0] * invs; st.y = o[1] * invs;
                st.z = o[2] * invs; st.w = o[3] * invs;
                *reinterpret_cast<float4*>(ob + mt2 * 16 + q * 4) = st;
            }
        }
    }
}

extern "C" void kernel_launch(void* const* d_in, const int* in_sizes, int n_in,
                              void* d_out, int out_size, void* d_ws, size_t ws_size,
                              hipStream_t stream) {
    const float* x  = (const float*)d_in[0];
    const float* Wq = (const float*)d_in[1];
    const float* bq = (const float*)d_in[2];
    const float* Wk = (const float*)d_in[3];
    const float* bk = (const float*)d_in[4];
    const float* Wv = (const float*)d_in[5];
    const float* bv = (const float*)d_in[6];
    float* out = (float*)d_out;

    ushort_t* WT = (ushort_t*)((char*)d_ws + WS_WT);

    k0_conv<<<dim3(96), dim3(256), 0, stream>>>(Wq, Wk, Wv, WT);
    k1_attn<<<dim3(2048), dim3(512), 0, stream>>>(x, WT, bq, bk, bv, out);
}

// Round 12
// 146.464 us; speedup vs baseline: 1.3586x; 1.2240x over previous
//
#include <hip/hip_runtime.h>

// ---------------------------------------------------------------------------
// Temporal MHA (MI355X/gfx950), B=256, S=176 (8t x 22j), D_in=128, H=8, Hd=32.
//  k0: W -> bf16 once (tiny, 96 blocks). x read fp32 directly by k1.
//  k1: block = (batch-pair, h), 704 thr = 11 waves, 2 blocks/CU (R9 structure
//      -- the 52 us champion; R10/R11 showed global W-gathers cost 2x).
//   p1: wave w = m-tile w for BOTH batches; W staged to LDS once (coalesced),
//       b128 frags read once per job, reused across batches. x fp32 float4
//       pairs -> in-reg bf16 (half-up). Q^T stays in regs (k-slot bijection,
//       R7-verified); K,V^T -> LDS permuted (R9-verified bank-uniform b128).
//   p2: per batch: S^T = K*Q^T (11 MFMA), mask, exp2-softmax (unnormalized,
//       1/sum in epilogue), P^T in regs, O^T = V^T*P^T (12 MFMA), f32 stores.
// k-slot bijection sigma(q,j) = (j<4 ? q*4+j : 16+q*4+(j-4)); KS col
// s=(c>>2)*8+nt*4+(c&3); VT col s=(w>>1)*32+(c>>2)*8+(w&1)*4+(c&3).
// VT pad slots (t' 176..191) zeroed across phys cols [160,192) (R9 fix).
// ---------------------------------------------------------------------------

#define SEQ    176
#define HD     32
#define DIN    128
#define DMODEL 256

typedef unsigned short ushort_t;
typedef __attribute__((ext_vector_type(8))) short short8;
typedef __attribute__((ext_vector_type(4))) short short4v;
typedef __attribute__((ext_vector_type(4))) float float4v;
typedef __attribute__((ext_vector_type(4))) unsigned short ushort4v;

// ws layout (bytes): WT bf16 [3][8][32][128] @ 0
#define WS_WT 0u

// LDS (ushort units), total 39936 ush = 79872 B -> 2 blocks/CU
//  WS @ 0      [3][32][136]     = 13056  (W slices, padded, phase 1)
//  KS @ 13056  [2][176][40]     = 14080  (K, permuted cols)
//  VT @ 27136  [2][32][200]     = 12800  (V^T, permuted cols; pad zeroed)
#define SMEM_TOTAL 39936
#define OFF_KS 13056
#define OFF_VT 27136
#define KS_B   7040
#define VT_B   6400

__device__ __forceinline__ ushort_t f2bf_rtne(float f) {
    union { float f; unsigned int u; } cv; cv.f = f;
    unsigned int u = cv.u;
    unsigned int rb = 0x7FFFu + ((u >> 16) & 1u);
    return (ushort_t)((u + rb) >> 16);
}
__device__ __forceinline__ ushort_t f2bf(float f) {   // round-half-up, 2 VALU
    union { float f; unsigned int u; } cv; cv.f = f;
    return (ushort_t)((cv.u + 0x8000u) >> 16);
}

// ---------------- k0: W -> WT bf16 [mat][h][n][k] (96 blocks) -------------
__global__ __launch_bounds__(256)
void k0_conv(const float* __restrict__ Wq, const float* __restrict__ Wk,
             const float* __restrict__ Wv, ushort_t* __restrict__ WT)
{
    int idx = blockIdx.x * 256 + threadIdx.x;     // < 24576
    int e = idx * 4;
    int mat = e >> 15, h = (e >> 12) & 7, n = (e >> 7) & 31, k = e & 127;
    const float* W = (mat == 0) ? Wq : ((mat == 1) ? Wk : Wv);
    ushort4v o;
    o.x = f2bf_rtne(W[(k + 0) * DMODEL + h * HD + n]);
    o.y = f2bf_rtne(W[(k + 1) * DMODEL + h * HD + n]);
    o.z = f2bf_rtne(W[(k + 2) * DMODEL + h * HD + n]);
    o.w = f2bf_rtne(W[(k + 3) * DMODEL + h * HD + n]);
    reinterpret_cast<ushort4v*>(WT)[idx] = o;
}

// ---------------- k1: fused attention (2 batches / block) -----------------
__global__ __launch_bounds__(704, 6)
void k1_attn(const float* __restrict__ x, const ushort_t* __restrict__ WT,
             const float* __restrict__ bq, const float* __restrict__ bk,
             const float* __restrict__ bv, float* __restrict__ out)
{
    __shared__ ushort_t smem[SMEM_TOTAL];
    ushort_t* WS = smem;                 // [3][32][136]
    ushort_t* KS = smem + OFF_KS;        // [2][176][40] permuted
    ushort_t* VT = smem + OFF_VT;        // [2][32][200] permuted

    const int tid  = threadIdx.x;
    const int lane = tid & 63;
    const int w    = tid >> 6;           // wave 0..10 = m-tile / row-tile
    const int c    = lane & 15;
    const int q    = lane >> 4;
    const int b0   = (blockIdx.x >> 3) * 2;
    const int h    = blockIdx.x & 7;

    // ---- stage W-slice (head h): 1536 chunks of 16 B, 16 chunks per n-row
#pragma unroll
    for (int it = 0; it < 3; ++it) {
        int c8 = tid + it * 704;
        if (c8 < 1536) {
            int mat = c8 >> 9, rem = c8 & 511, n = rem >> 4, kc = rem & 15;
            short8 v = *reinterpret_cast<const short8*>(
                WT + (size_t)(((mat * 8 + h) * 32 + n) * 128 + kc * 8));
            *reinterpret_cast<short8*>(WS + (mat * 32 + n) * 136 + kc * 8) = v;
        }
    }
    // zero ALL of VT physical cols [160,192) for both batches (permuted pad
    // slots interleave through this range; real w=10 writes land after the
    // barrier and overwrite their half).
    if (tid < 512) {
        int bb = tid >> 8, rem = tid & 255;
        int row = rem >> 3, ch = rem & 7;
        short4v z = {0, 0, 0, 0};
        *reinterpret_cast<short4v*>(VT + bb * VT_B + row * 200 + 160 + ch * 4) = z;
    }
    __syncthreads();   // barrier 0: cross-wave staging

    // ---- phase 1: QKV for m-tile w, both batches; x fp32 -> bf16 in-reg --
    short8 xf[2][4];
#pragma unroll
    for (int bb = 0; bb < 2; ++bb) {
        const float* xr = x + ((size_t)(b0 + bb) * SEQ + w * 16 + c) * DIN;
#pragma unroll
        for (int kk = 0; kk < 4; ++kk) {
            float4 a0 = *reinterpret_cast<const float4*>(xr + kk * 32 + q * 8);
            float4 a1 = *reinterpret_cast<const float4*>(xr + kk * 32 + q * 8 + 4);
            short8 v;
            v[0] = (short)f2bf(a0.x); v[1] = (short)f2bf(a0.y);
            v[2] = (short)f2bf(a0.z); v[3] = (short)f2bf(a0.w);
            v[4] = (short)f2bf(a1.x); v[5] = (short)f2bf(a1.y);
            v[6] = (short)f2bf(a1.z); v[7] = (short)f2bf(a1.w);
            xf[bb][kk] = v;
        }
    }

    const float qscale = 0.17677669529663687f * 1.4426950408889634f; // 1/sqrt(32)*log2e
    short8 qf8[2];
    const int skv = (c >> 2) * 8 + (c & 3);          // permuted col base (K)
    const int svt = (w >> 1) * 32 + (c >> 2) * 8 + (w & 1) * 4 + (c & 3); // (V)

#pragma unroll
    for (int jj = 0; jj < 6; ++jj) {
        const int mat = jj >> 1, nt = jj & 1;
        const ushort_t* wrow = WS + (mat * 32 + nt * 16 + c) * 136 + q * 8;
        short8 wf[4];
#pragma unroll
        for (int kk = 0; kk < 4; ++kk)
            wf[kk] = *reinterpret_cast<const short8*>(wrow + kk * 32);

#pragma unroll
        for (int bb = 0; bb < 2; ++bb) {
            float4v acc = {0.f, 0.f, 0.f, 0.f};
            if (mat == 1) {              // K normal: A=x, B=W
#pragma unroll
                for (int kk = 0; kk < 4; ++kk)
                    acc = __builtin_amdgcn_mfma_f32_16x16x32_bf16(xf[bb][kk], wf[kk], acc, 0, 0, 0);
            } else {                     // Q^T / V^T: A=W, B=x
#pragma unroll
                for (int kk = 0; kk < 4; ++kk)
                    acc = __builtin_amdgcn_mfma_f32_16x16x32_bf16(wf[kk], xf[bb][kk], acc, 0, 0, 0);
            }
            if (mat == 0) {
                float4 bb4 = *reinterpret_cast<const float4*>(bq + h * HD + nt * 16 + q * 4);
                qf8[bb][nt * 4 + 0] = (short)f2bf((acc[0] + bb4.x) * qscale);
                qf8[bb][nt * 4 + 1] = (short)f2bf((acc[1] + bb4.y) * qscale);
                qf8[bb][nt * 4 + 2] = (short)f2bf((acc[2] + bb4.z) * qscale);
                qf8[bb][nt * 4 + 3] = (short)f2bf((acc[3] + bb4.w) * qscale);
            } else if (mat == 1) {
                float bia = bk[h * HD + nt * 16 + c];
                ushort_t* ksb = KS + bb * KS_B;
#pragma unroll
                for (int r = 0; r < 4; ++r)
                    ksb[(w * 16 + q * 4 + r) * 40 + skv + nt * 4] = f2bf(acc[r] + bia);
            } else {
                float4 bb4 = *reinterpret_cast<const float4*>(bv + h * HD + nt * 16 + q * 4);
                ushort_t* vtb = VT + bb * VT_B;
#pragma unroll
                for (int r = 0; r < 4; ++r) {
                    float bias_r = (r == 0) ? bb4.x : (r == 1) ? bb4.y
                                  : (r == 2) ? bb4.z : bb4.w;
                    float v = acc[r] + bias_r;
                    v = v > 0.f ? v : 0.f;           // ReLU on V
                    vtb[(nt * 16 + q * 4 + r) * 200 + svt] = f2bf(v);
                }
            }
        }
    }
    __syncthreads();   // barrier 1: KS/VT complete

    // ---- phase 2: attention; lane(c,q) owns score column t = w*16+c ----
    const int t_row = w * 16 + c;
    const int lo = (t_row / 22) * 22;    // start of t's 22-joint time block

#pragma unroll
    for (int bb = 0; bb < 2; ++bb) {
        const ushort_t* KSb = KS + bb * KS_B;
        const ushort_t* VTb = VT + bb * VT_B;
        float su = 0.f;
        short8 pf[6];
        pf[5] = (short8){0, 0, 0, 0, 0, 0, 0, 0};   // n=11 pad half stays zero
#pragma unroll
        for (int n = 0; n < 11; ++n) {
            short8 kf = *reinterpret_cast<const short8*>(KSb + (n * 16 + c) * 40 + q * 8);
            float4v s = {0.f, 0.f, 0.f, 0.f};
            s = __builtin_amdgcn_mfma_f32_16x16x32_bf16(kf, qf8[bb], s, 0, 0, 0);
#pragma unroll
            for (int r = 0; r < 4; ++r) {
                int tp = n * 16 + q * 4 + r;
                float sv = (((unsigned)(tp - lo) < 22u) && (tp != t_row)) ? -1e30f : s[r];
                float e = __builtin_amdgcn_exp2f(sv);
                su += e;
                pf[n >> 1][(n & 1) * 4 + r] = (short)f2bf(e);
            }
        }
        su += __shfl_xor(su, 16, 64);    // reduce across the 4 quads
        su += __shfl_xor(su, 32, 64);
        const float invs = 1.0f / su;

        float* ob = out + ((size_t)(b0 + bb) * SEQ + t_row) * DMODEL + h * HD;
#pragma unroll
        for (int mt = 0; mt < 2; ++mt) {
            const ushort_t* vrow = VTb + (mt * 16 + c) * 200;
            float4v o = {0.f, 0.f, 0.f, 0.f};
#pragma unroll
            for (int g = 0; g < 6; ++g) {
                short8 vf = *reinterpret_cast<const short8*>(vrow + g * 32 + q * 8);
                o = __builtin_amdgcn_mfma_f32_16x16x32_bf16(vf, pf[g], o, 0, 0, 0);
            }
            float4 st;
            st.x = o[0] * invs; st.y = o[1] * invs;
            st.z = o[2] * invs; st.w = o[3] * invs;
            *reinterpret_cast<float4*>(ob + mt * 16 + q * 4) = st;
        }
    }
}

extern "C" void kernel_launch(void* const* d_in, const int* in_sizes, int n_in,
                              void* d_out, int out_size, void* d_ws, size_t ws_size,
                              hipStream_t stream) {
    const float* x  = (const float*)d_in[0];
    const float* Wq = (const float*)d_in[1];
    const float* bq = (const float*)d_in[2];
    const float* Wk = (const float*)d_in[3];
    const float* bk = (const float*)d_in[4];
    const float* Wv = (const float*)d_in[5];
    const float* bv = (const float*)d_in[6];
    float* out = (float*)d_out;

    ushort_t* WT = (ushort_t*)((char*)d_ws + WS_WT);

    k0_conv<<<dim3(96), dim3(256), 0, stream>>>(Wq, Wk, Wv, WT);
    k1_attn<<<dim3(1024), dim3(704), 0, stream>>>(x, WT, bq, bk, bv, out);
}